// Round 1
// 769.460 us; speedup vs baseline: 1.0702x; 1.0702x over previous
//
#include <hip/hip_runtime.h>

#define NPTS   300000
#define NPAIRS 100000
#define KOFF   27
#define CIN    32
#define COUT   64
#define NGROUP 8
#define EPSV   1e-5f
#define SLOPE  0.01f

#define PAIRS_PER_BLOCK 256
#define BLOCKS_PER_K ((NPAIRS + PAIRS_PER_BLOCK - 1) / PAIRS_PER_BLOCK)  // 391

// ---------------------------------------------------------------- zero
__global__ __launch_bounds__(256) void zero_kernel(float4* __restrict__ out4, int n4,
                                                   float* __restrict__ stats) {
    int i = blockIdx.x * blockDim.x + threadIdx.x;
    if (i < n4) out4[i] = make_float4(0.f, 0.f, 0.f, 0.f);
    if (blockIdx.x == 0 && threadIdx.x < 16) stats[threadIdx.x] = 0.f;
}

// ---------------------------------------------------------------- conv (gather-matmul-scatter)
// One wave processes a stream of pairs for a single kernel offset k.
// lane = output channel c. Weight column W[k][:, c] lives in 32 VGPRs.
// Pair row indices are wave-uniform -> feats row loads scalarize (s_load).
// Depth-2 software pipeline: row for pair p+1 is issued before pair p's FMAs,
// doubling memory-level parallelism per wave (the gather is HBM-latency-bound).
__global__ __launch_bounds__(256) void conv_kernel(
    const float* __restrict__ feats, const float* __restrict__ weight,
    const int* __restrict__ in_idx, const int* __restrict__ out_idx,
    float* __restrict__ out)
{
    const int lane = threadIdx.x & 63;
    const int wave = threadIdx.x >> 6;
    const int k     = blockIdx.x / BLOCKS_PER_K;
    const int pair0 = (blockIdx.x % BLOCKS_PER_K) * PAIRS_PER_BLOCK;

    // per-lane weight column, loaded once per block (coalesced across lanes)
    float w[CIN];
    const float* wk = weight + k * (CIN * COUT) + lane;
#pragma unroll
    for (int i = 0; i < CIN; ++i) w[i] = wk[i * COUT];

    const int per_wave = PAIRS_PER_BLOCK / 4;         // 64 pairs per wave
    int p    = pair0 + wave * per_wave;
    int pend = p + per_wave;
    if (pend > NPAIRS) pend = NPAIRS;
    if (p >= pend) return;

    const int* ii = in_idx  + k * NPAIRS;
    const int* oi = out_idx + k * NPAIRS;

    // prologue: row for first pair
    int rin0 = __builtin_amdgcn_readfirstlane(ii[p]);
    const float* f0 = feats + (size_t)rin0 * CIN;
    float a[CIN];
#pragma unroll
    for (int i = 0; i < CIN; ++i) a[i] = f0[i];

    for (; p + 1 < pend; ++p) {
        // issue next pair's row load (independent of current FMAs -> stays in flight)
        int rin1 = __builtin_amdgcn_readfirstlane(ii[p + 1]);
        const float* f1 = feats + (size_t)rin1 * CIN;
        float b[CIN];
#pragma unroll
        for (int i = 0; i < CIN; ++i) b[i] = f1[i];

        // compute current pair (two accumulator chains to shorten dep latency)
        int rout = __builtin_amdgcn_readfirstlane(oi[p]);
        float acc0 = 0.f, acc1 = 0.f;
#pragma unroll
        for (int i = 0; i < CIN; i += 2) {
            acc0 = fmaf(a[i],     w[i],     acc0);
            acc1 = fmaf(a[i + 1], w[i + 1], acc1);
        }
        atomicAdd(out + (size_t)rout * COUT + lane, acc0 + acc1);  // coalesced 256B

#pragma unroll
        for (int i = 0; i < CIN; ++i) a[i] = b[i];    // register rotate (free after SSA)
    }
    // epilogue: last pair
    {
        int rout = __builtin_amdgcn_readfirstlane(oi[p]);
        float acc0 = 0.f, acc1 = 0.f;
#pragma unroll
        for (int i = 0; i < CIN; i += 2) {
            acc0 = fmaf(a[i],     w[i],     acc0);
            acc1 = fmaf(a[i + 1], w[i + 1], acc1);
        }
        atomicAdd(out + (size_t)rout * COUT + lane, acc0 + acc1);
    }
}

// ---------------------------------------------------------------- group stats (sum, sumsq)
// float4 per thread (16 float4 per row -> channel block (i&15)*4, constant per thread
// since the grid stride is a multiple of 16). Wave shuffle-reduce -> LDS -> 16 atomics
// per BLOCK (was 16 per wave straight to 16 global counters = heavy contention).
__global__ __launch_bounds__(256) void stats_kernel(const float4* __restrict__ out4,
                                                    float* __restrict__ stats) {
    const int tid  = blockIdx.x * 256 + threadIdx.x;
    const int ntid = gridDim.x * 256;                 // multiple of 16
    const int n4   = NPTS * COUT / 4;

    float s = 0.f, ss = 0.f;
    for (int i = tid; i < n4; i += ntid) {
        float4 v = out4[i];
        s  += v.x + v.y + v.z + v.w;
        ss += v.x * v.x + v.y * v.y + v.z * v.z + v.w * v.w;
    }
    // group of this thread's float4: g = (lane&15)>>1, same for lanes l^1, l^16, l^32
    s  += __shfl_xor(s,  1, 64);  ss += __shfl_xor(ss,  1, 64);
    s  += __shfl_xor(s, 16, 64);  ss += __shfl_xor(ss, 16, 64);
    s  += __shfl_xor(s, 32, 64);  ss += __shfl_xor(ss, 32, 64);

    __shared__ float sm_s[4][NGROUP];
    __shared__ float sm_ss[4][NGROUP];
    const int lane = threadIdx.x & 63;
    const int wv   = threadIdx.x >> 6;
    if (lane < 16 && (lane & 1) == 0) {
        sm_s [wv][lane >> 1] = s;
        sm_ss[wv][lane >> 1] = ss;
    }
    __syncthreads();
    if (threadIdx.x < NGROUP) {
        float ts = 0.f, tss = 0.f;
#pragma unroll
        for (int wvi = 0; wvi < 4; ++wvi) { ts += sm_s[wvi][threadIdx.x]; tss += sm_ss[wvi][threadIdx.x]; }
        atomicAdd(stats + threadIdx.x,          ts);
        atomicAdd(stats + NGROUP + threadIdx.x, tss);
    }
}

// ---------------------------------------------------------------- normalize + affine + leaky relu
__global__ __launch_bounds__(256) void norm_kernel(float4* __restrict__ out4, int n4,
                                                   const float* __restrict__ stats,
                                                   const float* __restrict__ gamma,
                                                   const float* __restrict__ beta) {
    int i = blockIdx.x * blockDim.x + threadIdx.x;
    if (i >= n4) return;
    int c0 = (i & 15) * 4;              // first channel of this float4; stays in one group
    int g  = c0 >> 3;
    const float cnt = (float)NPTS * (COUT / NGROUP);
    float mean = stats[g] / cnt;
    float var  = stats[8 + g] / cnt - mean * mean;
    float inv  = rsqrtf(var + EPSV);
    float4 v  = out4[i];
    float4 ga = *(const float4*)(gamma + c0);
    float4 be = *(const float4*)(beta  + c0);
    float x;
    x = (v.x - mean) * inv * ga.x + be.x; v.x = x >= 0.f ? x : SLOPE * x;
    x = (v.y - mean) * inv * ga.y + be.y; v.y = x >= 0.f ? x : SLOPE * x;
    x = (v.z - mean) * inv * ga.z + be.z; v.z = x >= 0.f ? x : SLOPE * x;
    x = (v.w - mean) * inv * ga.w + be.w; v.w = x >= 0.f ? x : SLOPE * x;
    out4[i] = v;
}

// ---------------------------------------------------------------- launch
extern "C" void kernel_launch(void* const* d_in, const int* in_sizes, int n_in,
                              void* d_out, int out_size, void* d_ws, size_t ws_size,
                              hipStream_t stream) {
    const float* feats  = (const float*)d_in[0];
    const float* weight = (const float*)d_in[1];
    const float* gamma  = (const float*)d_in[2];
    const float* beta   = (const float*)d_in[3];
    const int*   in_idx = (const int*)d_in[4];
    const int*   out_idx= (const int*)d_in[5];
    float* out   = (float*)d_out;
    float* stats = (float*)d_ws;

    int n4 = out_size / 4;                 // 4.8M float4
    int zb = (n4 + 255) / 256;

    zero_kernel<<<zb, 256, 0, stream>>>((float4*)out, n4, stats);
    conv_kernel<<<KOFF * BLOCKS_PER_K, 256, 0, stream>>>(feats, weight, in_idx, out_idx, out);
    stats_kernel<<<2048, 256, 0, stream>>>((const float4*)out, stats);
    norm_kernel<<<zb, 256, 0, stream>>>((float4*)out, n4, stats, gamma, beta);
}